// Round 9
// baseline (1234.807 us; speedup 1.0000x reference)
//
#include <hip/hip_runtime.h>
#include <cstdint>

// PQ ADC search, MI355X round 9.
// Pair-fused u8 tables (32 pairs x 65536 x 32q = 64 MB, 2 MB/pair L2-resident):
// halves the distinct-line gather count (6.4e7 -> 3.2e7), which R1/R4 showed is
// the wall (~5 cyc/line/CU). Scan: codes staged once to LDS, 2 lanes/row 16B
// gathers, 4 rows/thread MLP. Quantized-domain tau (rank-12 + 33 slack,
// conservative). Exact fp32 refine (reference order, bit-identical) + bitonic.

#define BQ 32
#define MSUB 64
#define KSUB 256
#define KOUT 64
#define NSAMP 8192
#define TAU_RANK 12
#define CAP 8192
#define NSORT 8192
#define SROWS 512          // rows per scan block

__device__ __forceinline__ unsigned pack4(int4 a) {
    return (unsigned)(a.x & 255) | ((unsigned)(a.y & 255) << 8) |
           ((unsigned)(a.z & 255) << 16) | ((unsigned)(a.w & 255) << 24);
}

// packed-u16 accumulate: aL += (b0, b2), aH += (b1, b3)
__device__ __forceinline__ void acc8(unsigned v, unsigned& aL, unsigned& aH) {
#if defined(__has_builtin) && __has_builtin(__builtin_amdgcn_perm)
    aL += __builtin_amdgcn_perm(0u, v, 0x0C020C00u);
    aH += __builtin_amdgcn_perm(0u, v, 0x0C030C01u);
#else
    aL += v & 0x00FF00FFu;
    aH += (v >> 8) & 0x00FF00FFu;
#endif
}

// ---------------- K1: fp32 distance table, layout table[m][c][b] (2 MB) ----------------
__global__ __launch_bounds__(256) void build_table(const float* __restrict__ q,
                                                   const float* __restrict__ cw,
                                                   float* __restrict__ table) {
    int tid = blockIdx.x * 256 + threadIdx.x;      // 524288
    int b = tid & 31;
    int c = (tid >> 5) & 255;
    int m = tid >> 13;
    const float* qp = q + b * (MSUB * 4) + m * 4;
    const float* cp = cw + (m * KSUB + c) * 4;
    float s = 0.f;
#pragma unroll
    for (int d = 0; d < 4; ++d) { float t = qp[d] - cp[d]; s += t * t; }
    table[tid] = s;
}

// ---------------- K1b: per-(m,b) min + range ----------------
__global__ __launch_bounds__(256) void minmax_kernel(const float* __restrict__ table,
                                                     float* __restrict__ off,
                                                     float* __restrict__ rng) {
    int m = blockIdx.x >> 5, b = blockIdx.x & 31;
    int c = threadIdx.x;
    float v = table[(m * 256 + c) * 32 + b];
    __shared__ float smin[256], smax[256];
    smin[c] = v; smax[c] = v;
    __syncthreads();
    for (int s = 128; s > 0; s >>= 1) {
        if (c < s) {
            smin[c] = fminf(smin[c], smin[c + s]);
            smax[c] = fmaxf(smax[c], smax[c + s]);
        }
        __syncthreads();
    }
    if (c == 0) {
        off[m * 32 + b] = smin[0];
        rng[m * 32 + b] = smax[0] - smin[0];
    }
}

// ---------------- K1c: per-query pair scale ----------------
__global__ __launch_bounds__(64) void scale2_kernel(const float* __restrict__ rng,
                                                    float* __restrict__ s2) {
    int b = threadIdx.x;
    if (b >= BQ) return;
    float mx = 0.f;
    for (int p = 0; p < 32; ++p) {
        float r = rng[(2 * p) * 32 + b] + rng[(2 * p + 1) * 32 + b];
        mx = fmaxf(mx, r);
    }
    if (mx < 1e-20f) mx = 1e-20f;
    s2[b] = 254.5f / mx;
}

// ---------------- K1d: build pair table, u8, layout pairT[p][c1*256+c0][32q] ----------------
__global__ __launch_bounds__(256) void build_pairT(const float* __restrict__ table,
                                                   const float* __restrict__ off,
                                                   const float* __restrict__ s2,
                                                   uint4* __restrict__ pairT) {
    int p = blockIdx.x >> 8;
    int c1 = blockIdx.x & 255;
    int c0 = threadIdx.x;
    int m0 = 2 * p, m1 = 2 * p + 1;
    __shared__ float d1[32], off0s[32], s2s[32];
    if (c0 < 32) {
        int q = c0;
        d1[q] = table[(m1 * 256 + c1) * 32 + q] - off[m1 * 32 + q];
        off0s[q] = off[m0 * 32 + q];
        s2s[q] = s2[q];
    }
    __syncthreads();
    const float* t0 = table + (size_t)(m0 * 256 + c0) * 32;
    unsigned w[8];
#pragma unroll
    for (int i = 0; i < 8; ++i) {
        unsigned wv = 0;
#pragma unroll
        for (int k = 0; k < 4; ++k) {
            int q = 4 * i + k;
            float v = (t0[q] - off0s[q]) + d1[q];
            int qv = (int)floorf(v * s2s[q]);
            if (qv < 0) qv = 0;
            if (qv > 255) qv = 255;
            wv |= (unsigned)qv << (8 * k);
        }
        w[i] = wv;
    }
    size_t base = ((size_t)p << 16) + (size_t)c1 * 256 + c0;   // entry index
    uint4 A = {w[0], w[1], w[2], w[3]};
    uint4 B = {w[4], w[5], w[6], w[7]};
    pairT[base * 2] = A;
    pairT[base * 2 + 1] = B;
}

// ---------------- K2a: quantized pair sums for sampled rows ----------------
__global__ __launch_bounds__(256) void sample_qpair(const char* __restrict__ pairT,
                                                    const int* __restrict__ codes,
                                                    unsigned short* __restrict__ qsamp,
                                                    int stride, int offset) {
    int t = blockIdx.x * 256 + threadIdx.x;        // NSAMP*2 threads
    int j = t >> 1, h = t & 1;
    int n = j * stride + offset;
    const int* crow = codes + (long)n * MSUB;
    const char* tb = pairT + h * 16;
    unsigned A[8] = {0, 0, 0, 0, 0, 0, 0, 0};
    for (int p = 0; p < 32; ++p) {
        unsigned idx = (unsigned)crow[2 * p] | ((unsigned)crow[2 * p + 1] << 8);
        uint4 g = *(const uint4*)(tb + ((size_t)p << 21) + (size_t)idx * 32);
        acc8(g.x, A[0], A[1]); acc8(g.y, A[2], A[3]);
        acc8(g.z, A[4], A[5]); acc8(g.w, A[6], A[7]);
    }
#pragma unroll
    for (int i = 0; i < 4; ++i) {
        int b0 = h * 16 + 4 * i;
        qsamp[(b0 + 0) * NSAMP + j] = (unsigned short)(A[2 * i] & 0xFFFFu);
        qsamp[(b0 + 1) * NSAMP + j] = (unsigned short)(A[2 * i + 1] & 0xFFFFu);
        qsamp[(b0 + 2) * NSAMP + j] = (unsigned short)(A[2 * i] >> 16);
        qsamp[(b0 + 3) * NSAMP + j] = (unsigned short)(A[2 * i + 1] >> 16);
    }
}

// ---------------- K2b: 12th-smallest qsum per query via 2-level histogram ----------------
__global__ __launch_bounds__(256) void qtau_kernel(const unsigned short* __restrict__ qsamp,
                                                   unsigned* __restrict__ Qtau) {
    __shared__ int hist[256];
    __shared__ int csel, cbefore;
    int b = blockIdx.x, t = threadIdx.x;
    const unsigned short* q = qsamp + b * NSAMP;
    hist[t] = 0;
    __syncthreads();
    for (int i = t; i < NSAMP; i += 256) atomicAdd(&hist[q[i] >> 6], 1);
    __syncthreads();
    if (t == 0) {
        int c = 0, k = 0;
        for (; k < 255; ++k) { if (c + hist[k] >= TAU_RANK) break; c += hist[k]; }
        csel = k; cbefore = c;
    }
    __syncthreads();
    int sel = csel, before = cbefore;
    __syncthreads();
    hist[t] = 0;
    __syncthreads();
    for (int i = t; i < NSAMP; i += 256) {
        unsigned v = q[i];
        if ((int)(v >> 6) == sel) atomicAdd(&hist[v & 63], 1);
    }
    __syncthreads();
    if (t == 0) {
        int c = before, l = 0;
        for (; l < 63; ++l) { c += hist[l]; if (c >= TAU_RANK) break; }
        if (c < TAU_RANK) l = 63;
        unsigned q12 = ((unsigned)sel << 6) | (unsigned)l;
        unsigned Q = q12 + 33;                     // +32 pair-floor slack, +1 strict-less
        if (Q > 32767u) Q = 32767u;
        Qtau[b] = Q;
    }
}

// ---------------- K3: coarse scan over pair table ----------------
// Block: 512 rows; thread t: h = t&1 (query half), rl = t>>1; rows rl + r*128.
__global__ __launch_bounds__(256, 4) void coarse_scan(const char* __restrict__ pairT,
                                                      const int4* __restrict__ codes4,
                                                      const unsigned* __restrict__ Qtau,
                                                      int* __restrict__ cnt,
                                                      int* __restrict__ cidx,
                                                      int N) {
    __shared__ unsigned scodes[SROWS * 17];        // 34,816 B (pad-17)
    int t = threadIdx.x;
    long tile0 = (long)blockIdx.x * SROWS;

    // stage codes: 512 rows x 16 packed dwords (u8 codes), coalesced int4 reads
#pragma unroll
    for (int i = 0; i < 32; ++i) {
        int chunk = i * 256 + t;                   // 8192 chunks: row=chunk>>4, w=chunk&15
        long g = tile0 * 16 + chunk;
        unsigned w = 0;
        if (g < (long)N * 16) w = pack4(codes4[g]);
        scodes[(chunk >> 4) * 17 + (chunk & 15)] = w;
    }
    __syncthreads();

    int h = t & 1, rl = t >> 1;
    const char* tb = pairT + h * 16;

    unsigned acc[4][8];
#pragma unroll
    for (int r = 0; r < 4; ++r)
#pragma unroll
        for (int k = 0; k < 8; ++k) acc[r][k] = 0;

#pragma unroll 4
    for (int pp = 0; pp < 16; ++pp) {              // packed dword index (2 pairs each)
        unsigned w[4];
#pragma unroll
        for (int r = 0; r < 4; ++r) w[r] = scodes[(rl + r * 128) * 17 + pp];
#pragma unroll
        for (int par = 0; par < 2; ++par) {
            int p = 2 * pp + par;
            const char* tp = tb + ((size_t)p << 21);
            uint4 g[4];
#pragma unroll
            for (int r = 0; r < 4; ++r) {
                unsigned idx = par ? (w[r] >> 16) : (w[r] & 0xFFFFu);
                g[r] = *(const uint4*)(tp + (size_t)idx * 32);
            }
#pragma unroll
            for (int r = 0; r < 4; ++r) {
                acc8(g[r].x, acc[r][0], acc[r][1]);
                acc8(g[r].y, acc[r][2], acc[r][3]);
                acc8(g[r].z, acc[r][4], acc[r][5]);
                acc8(g[r].w, acc[r][6], acc[r][7]);
            }
        }
    }

    unsigned TL[4], TH[4];
#pragma unroll
    for (int i = 0; i < 4; ++i) {
        int b0 = h * 16 + 4 * i;
        TL[i] = Qtau[b0] | (Qtau[b0 + 2] << 16);
        TH[i] = Qtau[b0 + 1] | (Qtau[b0 + 3] << 16);
    }
#pragma unroll
    for (int r = 0; r < 4; ++r) {
        long n = tile0 + rl + (long)r * 128;
        if (n >= N) continue;
        unsigned sb = 0;
#pragma unroll
        for (int i = 0; i < 4; ++i) {
            sb |= ~((acc[r][2 * i] | 0x80008000u) - TL[i]);
            sb |= ~((acc[r][2 * i + 1] | 0x80008000u) - TH[i]);
        }
        if (sb & 0x80008000u) {
#pragma unroll
            for (int i = 0; i < 4; ++i) {
                int b0 = h * 16 + 4 * i;
                unsigned al = acc[r][2 * i], ah = acc[r][2 * i + 1];
                unsigned tl = TL[i], th = TH[i];
                if ((al & 0xFFFFu) < (tl & 0xFFFFu)) {
                    int p = atomicAdd(&cnt[b0 + 0], 1);
                    if (p < CAP) cidx[(b0 + 0) * CAP + p] = (int)n;
                }
                if ((ah & 0xFFFFu) < (th & 0xFFFFu)) {
                    int p = atomicAdd(&cnt[b0 + 1], 1);
                    if (p < CAP) cidx[(b0 + 1) * CAP + p] = (int)n;
                }
                if ((al >> 16) < (tl >> 16)) {
                    int p = atomicAdd(&cnt[b0 + 2], 1);
                    if (p < CAP) cidx[(b0 + 2) * CAP + p] = (int)n;
                }
                if ((ah >> 16) < (th >> 16)) {
                    int p = atomicAdd(&cnt[b0 + 3], 1);
                    if (p < CAP) cidx[(b0 + 3) * CAP + p] = (int)n;
                }
            }
        }
    }
}

// ---------------- K4: exact refine (reference summation order, bit-identical) ----------------
__global__ __launch_bounds__(256) void refine(const float* __restrict__ table,
                                              const int* __restrict__ codes,
                                              const int* __restrict__ cnt,
                                              const int* __restrict__ cidx,
                                              float* __restrict__ cdist) {
    int b = blockIdx.y;
    int pos = blockIdx.x * 256 + threadIdx.x;
    int mc = cnt[b]; if (mc > CAP) mc = CAP;
    if (pos >= mc) return;
    int n = cidx[b * CAP + pos];
    const int4* cr = (const int4*)(codes + (long)n * MSUB);
    const float* tb = table + b;
    float s = 0.f;
#pragma unroll
    for (int w = 0; w < 16; w += 2) {
        int4 ca = cr[w], cb = cr[w + 1];
        float v0 = tb[(size_t)((w * 4 + 0) * 256 + ca.x) * 32];
        float v1 = tb[(size_t)((w * 4 + 1) * 256 + ca.y) * 32];
        float v2 = tb[(size_t)((w * 4 + 2) * 256 + ca.z) * 32];
        float v3 = tb[(size_t)((w * 4 + 3) * 256 + ca.w) * 32];
        float v4 = tb[(size_t)((w * 4 + 4) * 256 + cb.x) * 32];
        float v5 = tb[(size_t)((w * 4 + 5) * 256 + cb.y) * 32];
        float v6 = tb[(size_t)((w * 4 + 6) * 256 + cb.z) * 32];
        float v7 = tb[(size_t)((w * 4 + 7) * 256 + cb.w) * 32];
        s += v0; s += v1; s += v2; s += v3;        // sequential m order: bit-exact
        s += v4; s += v5; s += v6; s += v7;
    }
    cdist[b * CAP + pos] = s;
}

// ---------------- K5: per-query exact top-k, adaptive-size bitonic sort ----------------
__global__ __launch_bounds__(512) void final_topk(const int* __restrict__ cnt,
                                                  const int* __restrict__ cidx,
                                                  const float* __restrict__ cdist,
                                                  float* __restrict__ out) {
    __shared__ unsigned long long keys[NSORT];     // 64 KB
    int b = blockIdx.x;
    int m = cnt[b];
    if (m > NSORT) m = NSORT;
    int S = (m <= 2048) ? 2048 : NSORT;
    for (int i = threadIdx.x; i < S; i += 512) {
        unsigned long long k;
        if (i < m)
            k = ((unsigned long long)__float_as_uint(cdist[b * CAP + i]) << 32) |
                (unsigned)cidx[b * CAP + i];
        else
            k = ~0ULL;
        keys[i] = k;
    }
    __syncthreads();
    for (int kk = 2; kk <= S; kk <<= 1) {
        for (int jj = kk >> 1; jj > 0; jj >>= 1) {
            for (int i = threadIdx.x; i < S; i += 512) {
                int ixj = i ^ jj;
                if (ixj > i) {
                    unsigned long long a = keys[i], c = keys[ixj];
                    bool up = ((i & kk) == 0);
                    if ((a > c) == up) { keys[i] = c; keys[ixj] = a; }
                }
            }
            __syncthreads();
        }
    }
    for (int r = threadIdx.x; r < KOUT; r += 512) {
        unsigned long long k = keys[r];
        out[b * KOUT + r] = __uint_as_float((unsigned)(k >> 32));
        out[BQ * KOUT + b * KOUT + r] = (float)(unsigned)(k & 0xFFFFFFFFu);
    }
}

extern "C" void kernel_launch(void* const* d_in, const int* in_sizes, int n_in,
                              void* d_out, int out_size, void* d_ws, size_t ws_size,
                              hipStream_t stream) {
    const float* querys    = (const float*)d_in[0];
    const float* codewords = (const float*)d_in[1];
    const int*   codes     = (const int*)d_in[2];
    float* out = (float*)d_out;
    int N = in_sizes[2] / MSUB;                    // 1,000,000

    char* ws = (char*)d_ws;
    float*          table = (float*)(ws);                        // [0, 2 MB)
    unsigned short* qsamp = (unsigned short*)(ws + (2u << 20));  // [2, 2.5 MB)
    char*           small = ws + (3u << 20);
    float*    s2    = (float*)(small + 0);                       // 128 B
    unsigned* Qtau  = (unsigned*)(small + 128);                  // 128 B
    int*      cnt   = (int*)(small + 512);                       // 128 B
    float*    off   = (float*)(small + 4096);                    // 8 KB
    float*    rng   = (float*)(small + 12288);                   // 8 KB
    int*      cidx  = (int*)(ws + (4u << 20));                   // [4, 5 MB)
    float*    cdist = (float*)(ws + (5u << 20));                 // [5, 6 MB)
    char*     pairT = ws + (6u << 20);                           // [6, 70 MB)

    hipMemsetAsync(cnt, 0, 128, stream);

    build_table<<<(MSUB * KSUB * BQ) / 256, 256, 0, stream>>>(querys, codewords, table);
    minmax_kernel<<<MSUB * BQ, 256, 0, stream>>>(table, off, rng);
    scale2_kernel<<<1, 64, 0, stream>>>(rng, s2);
    build_pairT<<<32 * 256, 256, 0, stream>>>(table, off, s2, (uint4*)pairT);

    int stride = N / NSAMP;                        // 122
    int offset = 17;                               // max n = 8191*122+17 < N
    sample_qpair<<<NSAMP * 2 / 256, 256, 0, stream>>>(pairT, codes, qsamp, stride, offset);
    qtau_kernel<<<BQ, 256, 0, stream>>>(qsamp, Qtau);

    int tiles = (N + SROWS - 1) / SROWS;           // 1954
    coarse_scan<<<tiles, 256, 0, stream>>>(pairT, (const int4*)codes, Qtau, cnt, cidx, N);

    dim3 rgrid(CAP / 256, BQ);
    refine<<<rgrid, 256, 0, stream>>>(table, codes, cnt, cidx, cdist);

    final_topk<<<BQ, 512, 0, stream>>>(cnt, cidx, cdist, out);
}